// Round 1
// baseline (42.903 us; speedup 1.0000x reference)
//
#include <hip/hip_runtime.h>
#include <math.h>

#define THREADS 256
#define N_ATOMS 2048

// One block per batch. Computes R = y'^T y (3x3), squared norms, then
// lambda_max of the Theobald 4x4 key matrix via QCP Newton iteration.
__global__ __launch_bounds__(THREADS) void rmsd_batch_kernel(
    const float* __restrict__ yp, const float* __restrict__ yy,
    double* __restrict__ sd)
{
    const int b = blockIdx.x;
    const int t = threadIdx.x;
    const float4* A  = reinterpret_cast<const float4*>(yp + (size_t)b * (N_ATOMS * 3));
    const float4* Bv = reinterpret_cast<const float4*>(yy + (size_t)b * (N_ATOMS * 3));

    float sxx = 0.f, sxy = 0.f, sxz = 0.f;
    float syx = 0.f, syy = 0.f, syz = 0.f;
    float szx = 0.f, szy = 0.f, szz = 0.f;
    float na = 0.f, nb = 0.f;

    // 6144 floats/batch/input = 1536 float4 = 512 groups of 3 float4 (4 points each).
    // 256 threads x 2 iterations.
    #pragma unroll
    for (int it = 0; it < 2; ++it) {
        const int g = t + it * THREADS;
        const float4 a0 = A[3 * g + 0];
        const float4 a1 = A[3 * g + 1];
        const float4 a2 = A[3 * g + 2];
        const float4 b0 = Bv[3 * g + 0];
        const float4 b1 = Bv[3 * g + 1];
        const float4 b2 = Bv[3 * g + 2];

        float px[4], py[4], pz[4], qx[4], qy[4], qz[4];
        px[0] = a0.x; py[0] = a0.y; pz[0] = a0.z;
        px[1] = a0.w; py[1] = a1.x; pz[1] = a1.y;
        px[2] = a1.z; py[2] = a1.w; pz[2] = a2.x;
        px[3] = a2.y; py[3] = a2.z; pz[3] = a2.w;
        qx[0] = b0.x; qy[0] = b0.y; qz[0] = b0.z;
        qx[1] = b0.w; qy[1] = b1.x; qz[1] = b1.y;
        qx[2] = b1.z; qy[2] = b1.w; qz[2] = b2.x;
        qx[3] = b2.y; qy[3] = b2.z; qz[3] = b2.w;

        #pragma unroll
        for (int k = 0; k < 4; ++k) {
            sxx += px[k] * qx[k]; sxy += px[k] * qy[k]; sxz += px[k] * qz[k];
            syx += py[k] * qx[k]; syy += py[k] * qy[k]; syz += py[k] * qz[k];
            szx += pz[k] * qx[k]; szy += pz[k] * qy[k]; szz += pz[k] * qz[k];
            na  += px[k] * px[k] + py[k] * py[k] + pz[k] * pz[k];
            nb  += qx[k] * qx[k] + qy[k] * qy[k] + qz[k] * qz[k];
        }
    }

    float vals[11] = {sxx, sxy, sxz, syx, syy, syz, szx, szy, szz, na, nb};
    #pragma unroll
    for (int k = 0; k < 11; ++k) {
        #pragma unroll
        for (int off = 32; off > 0; off >>= 1)
            vals[k] += __shfl_down(vals[k], off, 64);
    }

    __shared__ float red[4][11];
    const int wave = t >> 6, lane = t & 63;
    if (lane == 0) {
        #pragma unroll
        for (int k = 0; k < 11; ++k) red[wave][k] = vals[k];
    }
    __syncthreads();

    if (t == 0) {
        double S[11];
        #pragma unroll
        for (int k = 0; k < 11; ++k)
            S[k] = (double)red[0][k] + (double)red[1][k] +
                   (double)red[2][k] + (double)red[3][k];
        const double Sxx = S[0], Sxy = S[1], Sxz = S[2];
        const double Syx = S[3], Syy = S[4], Syz = S[5];
        const double Szx = S[6], Szy = S[7], Szz = S[8];
        const double sqn = S[9] + S[10];

        // QCP characteristic polynomial: x^4 + C2 x^2 + C1 x + C0
        const double Sxx2 = Sxx * Sxx, Syy2 = Syy * Syy, Szz2 = Szz * Szz;
        const double Sxy2 = Sxy * Sxy, Syz2 = Syz * Syz, Sxz2 = Sxz * Sxz;
        const double Syx2 = Syx * Syx, Szy2 = Szy * Szy, Szx2 = Szx * Szx;

        const double SyzSzymSyySzz2 = 2.0 * (Syz * Szy - Syy * Szz);
        const double Sxx2Syy2Szz2Syz2Szy2 = Syy2 + Szz2 - Sxx2 + Syz2 + Szy2;

        const double C2 = -2.0 * (Sxx2 + Syy2 + Szz2 + Sxy2 + Syx2 + Sxz2 + Szx2 + Syz2 + Szy2);
        const double C1 = 8.0 * (Sxx * Syz * Szy + Syy * Szx * Sxz + Szz * Sxy * Syx -
                                 Sxx * Syy * Szz - Syz * Szx * Sxy - Szy * Syx * Sxz);

        const double SxzpSzx = Sxz + Szx;
        const double SyzpSzy = Syz + Szy;
        const double SxypSyx = Sxy + Syx;
        const double SyzmSzy = Syz - Szy;
        const double SxzmSzx = Sxz - Szx;
        const double SxymSyx = Sxy - Syx;
        const double SxxpSyy = Sxx + Syy;
        const double SxxmSyy = Sxx - Syy;
        const double Sxy2Sxz2Syx2Szx2 = Sxy2 + Sxz2 - Syx2 - Szx2;

        const double C0 =
            Sxy2Sxz2Syx2Szx2 * Sxy2Sxz2Syx2Szx2
            + (Sxx2Syy2Szz2Syz2Szy2 + SyzSzymSyySzz2) * (Sxx2Syy2Szz2Syz2Szy2 - SyzSzymSyySzz2)
            + (-(SxzpSzx) * (SyzmSzy) + (SxymSyx) * (SxxmSyy - Szz)) *
              (-(SxzmSzx) * (SyzpSzy) + (SxymSyx) * (SxxmSyy + Szz))
            + (-(SxzpSzx) * (SyzpSzy) - (SxypSyx) * (SxxpSyy - Szz)) *
              (-(SxzmSzx) * (SyzmSzy) - (SxypSyx) * (SxxpSyy + Szz))
            + (+(SxypSyx) * (SyzpSzy) + (SxzpSzx) * (SxxmSyy + Szz)) *
              (-(SxymSyx) * (SyzmSzy) + (SxzpSzx) * (SxxpSyy + Szz))
            + (+(SxypSyx) * (SyzmSzy) + (SxzmSzx) * (SxxmSyy - Szz)) *
              (-(SxymSyx) * (SyzpSzy) + (SxzmSzx) * (SxxpSyy - Szz));

        // Newton from E0 = (GA+GB)/2 >= lambda_max; monotone convergence (all roots real).
        double lam = 0.5 * sqn;
        for (int i = 0; i < 100; ++i) {
            const double old = lam;
            const double x2 = lam * lam;
            const double bp = (x2 + C2) * lam;
            const double ap = bp + C1;
            const double den = 2.0 * x2 * lam + bp + ap;
            if (den == 0.0) break;
            lam -= (ap * lam + C0) / den;
            if (fabs(lam - old) < fabs(1e-13 * lam)) break;
        }
        sd[b] = sqn - 2.0 * lam;
    }
}

__global__ __launch_bounds__(256) void rmsd_final_kernel(
    const double* __restrict__ sd, int Bn, float* __restrict__ out)
{
    const int t = threadIdx.x;
    double s = 0.0;
    for (int i = t; i < Bn; i += 256) s += sd[i];
    #pragma unroll
    for (int off = 32; off > 0; off >>= 1)
        s += __shfl_down(s, off, 64);
    __shared__ double red[4];
    if ((t & 63) == 0) red[t >> 6] = s;
    __syncthreads();
    if (t == 0) {
        const double tot = red[0] + red[1] + red[2] + red[3];
        out[0] = (float)sqrt(tot / (double)N_ATOMS);
    }
}

extern "C" void kernel_launch(void* const* d_in, const int* in_sizes, int n_in,
                              void* d_out, int out_size, void* d_ws, size_t ws_size,
                              hipStream_t stream) {
    const float* yp = (const float*)d_in[0];
    const float* yy = (const float*)d_in[1];
    float* out = (float*)d_out;
    const int B = in_sizes[0] / (N_ATOMS * 3);   // 4096

    double* sd = (double*)d_ws;                  // B doubles = 32 KB scratch

    rmsd_batch_kernel<<<B, THREADS, 0, stream>>>(yp, yy, sd);
    rmsd_final_kernel<<<1, 256, 0, stream>>>(sd, B, out);
}